// Round 10
// baseline (492.654 us; speedup 1.0000x reference)
//
#include <hip/hip_runtime.h>

typedef __attribute__((ext_vector_type(4))) float f32x4;
typedef __attribute__((ext_vector_type(8))) short short8;

#define C_    512
#define HW_   1024
#define M_    2048
#define NEG_INF (-1e30f)

__device__ __forceinline__ unsigned short f2bf(float f) {
    unsigned u = __builtin_bit_cast(unsigned, f);
    u += 0x7fffu + ((u >> 16) & 1u);     // RNE
    return (unsigned short)(u >> 16);
}
__device__ __forceinline__ float bf2f(unsigned short s) {
    return __builtin_bit_cast(float, (unsigned)s << 16);
}
__device__ __forceinline__ float pkval(unsigned u) {
    return __builtin_bit_cast(float, u & 0xFFFF0000u);
}

__device__ __forceinline__ void insert8(float v, int idx, float* sv, int* si) {
    sv[0] = v; si[0] = idx;
#pragma unroll
    for (int p = 0; p < 7; ++p) {
        if (sv[p] > sv[p + 1]) {
            float tv = sv[p]; sv[p] = sv[p + 1]; sv[p + 1] = tv;
            int   ti = si[p]; si[p] = si[p + 1]; si[p + 1] = ti;
        }
    }
}

// ---- repack mempool [2048][512] f32 -> membR bf16, kc-major (32ch chunks) ----
__global__ __launch_bounds__(256) void convk(const float* __restrict__ in,
                                             unsigned short* __restrict__ ob) {
    int gid = blockIdx.x * 256 + threadIdx.x;
    int m  = gid >> 6;
    int ug = gid & 63;
    const float4* p = (const float4*)(in + (size_t)m * C_ + ug * 8);
    float4 v0 = p[0], v1 = p[1];
    int4 o;
    o.x = (int)f2bf(v0.x) | ((int)f2bf(v0.y) << 16);
    o.y = (int)f2bf(v0.z) | ((int)f2bf(v0.w) << 16);
    o.z = (int)f2bf(v1.x) | ((int)f2bf(v1.y) << 16);
    o.w = (int)f2bf(v1.z) | ((int)f2bf(v1.w) << 16);
    int kc = ug >> 2, u = ug & 3;
    *(int4*)((char*)ob + (size_t)kc * 131072 + m * 64 + (u << 4)) = o;
}

// ---------------- kernel 2: 128x128 GEMM tile + exact per-tile top-8 ----------------
#define K2_ABUF  9216                   // 128 rows * 72B (32ch bf16 + 8 pad)
#define K2_CAND  33792                  // att16 [128][132]u16 = 33792 overlays A dbuf
#define K2_ARENA 41984                  // + candt [128][2][8]u32 = 8192

__global__ __launch_bounds__(256, 2) void gemmk(const float* __restrict__ x,
                                                const unsigned short* __restrict__ membR,
                                                unsigned int* __restrict__ gcand) {
    __shared__ __align__(16) char arena[K2_ARENA];
    unsigned short* att16 = (unsigned short*)arena;
    unsigned int*   candt = (unsigned int*)(arena + K2_CAND);

    const int t   = threadIdx.x;
    const int l   = t & 63;
    const int w   = t >> 6;
    const int hi  = l >> 4;
    const int l15 = l & 15;
    const int colTile = blockIdx.x;       // 0..15
    const int rowTile = blockIdx.y;       // 0..255
    const int n0  = rowTile * 128;
    const int b   = n0 >> 10;
    const int hw0 = n0 & 1023;
    const float* xb = x + (size_t)b * C_ * HW_ + hw0;

    // B fragment base: item = colTile*128 + itf*16 + l15, k-quarter hi
    const char* bbase = (const char*)membR + colTile * 8192 + l15 * 64 + hi * 16;

    // prefetch B kc=0
    short8 bq[8], bn[8];
#pragma unroll
    for (int itf = 0; itf < 8; ++itf) bq[itf] = *(const short8*)(bbase + itf * 1024);

    // stage A kc=0 into buf0
    {
        char* buf = arena;
#pragma unroll
        for (int cc = 0; cc < 8; cc += 2) {
            int c = w * 8 + cc;
#pragma unroll
            for (int rr = 0; rr < 2; ++rr) {
                int row = rr * 64 + l;
                float f0 = xb[(size_t)c * HW_ + row];
                float f1 = xb[(size_t)(c + 1) * HW_ + row];
                unsigned pk = (unsigned)f2bf(f0) | ((unsigned)f2bf(f1) << 16);
                *(unsigned*)(buf + row * 72 + c * 2) = pk;
            }
        }
    }
    __syncthreads();

    f32x4 acc[2][8];
#pragma unroll
    for (int rf = 0; rf < 2; ++rf)
#pragma unroll
        for (int itf = 0; itf < 8; ++itf) acc[rf][itf] = (f32x4)0.f;

#pragma unroll 2
    for (int kc = 0; kc < 16; ++kc) {
        // stage A kc+1 into other buffer
        if (kc < 15) {
            char* buf = arena + ((kc + 1) & 1) * K2_ABUF;
            const float* xc = xb + (size_t)(kc + 1) * 32 * HW_;
#pragma unroll
            for (int cc = 0; cc < 8; cc += 2) {
                int c = w * 8 + cc;
#pragma unroll
                for (int rr = 0; rr < 2; ++rr) {
                    int row = rr * 64 + l;
                    float f0 = xc[(size_t)c * HW_ + row];
                    float f1 = xc[(size_t)(c + 1) * HW_ + row];
                    unsigned pk = (unsigned)f2bf(f0) | ((unsigned)f2bf(f1) << 16);
                    *(unsigned*)(buf + row * 72 + c * 2) = pk;
                }
            }
        }
        // prefetch B kc+1
        {
            int s = (kc + 1 < 16) ? kc + 1 : 15;
            const char* pn = bbase + (size_t)s * 131072;
#pragma unroll
            for (int itf = 0; itf < 8; ++itf) bn[itf] = *(const short8*)(pn + itf * 1024);
        }
        // A frags from current buffer
        const char* cur = arena + (kc & 1) * K2_ABUF;
        short8 a0 = *(const short8*)(cur + (w * 32 + l15) * 72 + hi * 16);
        short8 a1 = *(const short8*)(cur + (w * 32 + 16 + l15) * 72 + hi * 16);
#pragma unroll
        for (int itf = 0; itf < 8; ++itf) {
            acc[0][itf] = __builtin_amdgcn_mfma_f32_16x16x32_bf16(a0, bq[itf], acc[0][itf], 0, 0, 0);
            acc[1][itf] = __builtin_amdgcn_mfma_f32_16x16x32_bf16(a1, bq[itf], acc[1][itf], 0, 0, 0);
        }
#pragma unroll
        for (int itf = 0; itf < 8; ++itf) bq[itf] = bn[itf];
        __syncthreads();
    }

    // ---- dump att bf16 [128][132] (overlays A dbuf; final barrier passed) ----
#pragma unroll
    for (int rf = 0; rf < 2; ++rf)
#pragma unroll
        for (int itf = 0; itf < 8; ++itf) {
            int col = itf * 16 + l15;
#pragma unroll
            for (int reg = 0; reg < 4; ++reg) {
                int row = w * 32 + rf * 16 + hi * 4 + reg;
                att16[row * 132 + col] = f2bf(acc[rf][itf][reg]);
            }
        }
    __syncthreads();

    // ---- scan: 2 threads/row, 64 items each (vectorized + max-prune) ----
    const int sr = t >> 1, hf = t & 1;
    float sv[8]; int si[8];
#pragma unroll
    for (int p = 0; p < 8; ++p) { sv[p] = NEG_INF; si[p] = 0x7fffffff; }
    {
        const unsigned short* arow = att16 + sr * 132 + hf * 64;
#pragma unroll
        for (int v = 0; v < 8; ++v) {
            short8 pv = *(const short8*)(arow + v * 8);
            float f[8];
#pragma unroll
            for (int e = 0; e < 8; ++e) f[e] = bf2f((unsigned short)pv[e]);
            float m01 = fmaxf(f[0], f[1]), m23 = fmaxf(f[2], f[3]);
            float m45 = fmaxf(f[4], f[5]), m67 = fmaxf(f[6], f[7]);
            float vmax = fmaxf(fmaxf(m01, m23), fmaxf(m45, m67));
            if (vmax > sv[0]) {
#pragma unroll
                for (int e = 0; e < 8; ++e)
                    if (f[e] > sv[0]) insert8(f[e], hf * 64 + v * 8 + e, sv, si);
            }
        }
    }
    __syncthreads();   // att dead; candt region separate
    // pack candidates: val bf16 bits | global item idx (u16)
#pragma unroll
    for (int p = 0; p < 8; ++p)
        candt[(sr * 2 + hf) * 8 + p] =
            (__builtin_bit_cast(unsigned, sv[p]) & 0xFFFF0000u) |
            (unsigned)(colTile * 128 + si[p]);
    __syncthreads();

    // ---- leader per row: merge 2 sorted-8 lists -> exact tile top-8, write gcand ----
    if (t < 128) {
        const unsigned* c0 = candt + (t * 2 + 0) * 8;
        const unsigned* c1 = candt + (t * 2 + 1) * 8;
        int p0 = 7, p1 = 7;
        unsigned res[8];
#pragma unroll
        for (int s = 0; s < 8; ++s) {
            unsigned u0 = c0[p0 < 0 ? 0 : p0], u1 = c1[p1 < 0 ? 0 : p1];
            float v0 = (p0 >= 0) ? pkval(u0) : NEG_INF;
            float v1 = (p1 >= 0) ? pkval(u1) : NEG_INF;
            bool take0 = (v0 > v1) || (v0 == v1 && (int)(u0 & 0xFFFFu) < (int)(u1 & 0xFFFFu));
            if (p1 < 0) take0 = true;
            if (p0 < 0) take0 = false;
            if (take0) { res[s] = u0; --p0; } else { res[s] = u1; --p1; }
        }
        unsigned int* gp = gcand + (size_t)(n0 + t) * 128 + colTile * 8;
        *(uint4*)gp       = make_uint4(res[0], res[1], res[2], res[3]);
        *(uint4*)(gp + 4) = make_uint4(res[4], res[5], res[6], res[7]);
    }
}

// ---------------- kernel 3: merge 128 cands -> top-16 -> refine -> combine ----------------
#define QS 260
#define K3_SEL 33280
#define K3_RFV 35328
#define K3_WL  37376
#define K3_IL  38400
#define K3_ARENA 39424
#define NCAND 16

__global__ __launch_bounds__(256, 4) void mergek(const float* __restrict__ x,
                                                 const float* __restrict__ mempool,
                                                 const unsigned int* __restrict__ gcand,
                                                 float* __restrict__ out) {
    __shared__ __align__(16) char arena[K3_ARENA];
    float* candv  = (float*)arena;                   // [32][33], dead before qs
    int*   candi  = (int*)(arena + 4224);            // [32][33]
    float* qs     = (float*)arena;                   // [32][260] refine overlay
    int*   selidx = (int*)(arena + K3_SEL);          // [32][16]
    float* refv   = (float*)(arena + K3_RFV);        // [32][16]
    float* w_lds  = (float*)(arena + K3_WL);         // [32][8]
    int*   i_lds  = (int*)(arena + K3_IL);           // [32][8]

    const int t   = threadIdx.x;
    const int n0  = blockIdx.x * 32;
    const int b   = n0 >> 10;
    const int hw0 = n0 & 1023;
    const float* xb = x + (size_t)b * C_ * HW_ + hw0;

    // ---- scan 128 global candidates: 4 threads/row x 32 ----
    const int srow = t >> 2, stq = t & 3;
    float sv[8]; int si[8];
#pragma unroll
    for (int p = 0; p < 8; ++p) { sv[p] = NEG_INF; si[p] = 0x7fffffff; }
    if (t < 128) {
        const unsigned int* gc = gcand + (size_t)(n0 + srow) * 128 + stq * 32;
#pragma unroll 4
        for (int j = 0; j < 32; ++j) {
            unsigned u = gc[j];
            float v = pkval(u);
            if (v > sv[0]) insert8(v, (int)(u & 0xFFFFu), sv, si);
        }
#pragma unroll
        for (int p = 0; p < 8; ++p) {
            candv[srow * 33 + stq * 8 + p] = sv[p];
            candi[srow * 33 + stq * 8 + p] = si[p];
        }
    }
    __syncthreads();

    // ---- leader: 4-way merge of sorted lists -> approx top-16 ----
    if (t < 32) {
        const int row = t;
        int pos[4] = {7, 7, 7, 7};
        for (int s = 0; s < NCAND; ++s) {
            float vb = NEG_INF; int ib = 0x7fffffff; int qb = 0;
#pragma unroll
            for (int q = 0; q < 4; ++q) {
                if (pos[q] >= 0) {
                    float v = candv[row * 33 + q * 8 + pos[q]];
                    int  ii = candi[row * 33 + q * 8 + pos[q]];
                    if (v > vb || (v == vb && ii < ib)) { vb = v; ib = ii; qb = q; }
                }
            }
            selidx[row * NCAND + s] = ib;
#pragma unroll
            for (int q = 0; q < 4; ++q) if (q == qb) --pos[q];
        }
    }
    __syncthreads();

    // ---- exact fp32 refine: 2 chunks of 256 ch; pair p = t + 256*pp ----
    int cnd[2];
    cnd[0] = selidx[t];
    cnd[1] = selidx[t + 256];
    float racc[2] = {0.f, 0.f};
#pragma unroll
    for (int ch = 0; ch < 2; ++ch) {
        const int c0 = ch * 256;
        __syncthreads();               // candv dead / prior qs reads done
        {
            const int qr = t & 31, qg = t >> 5;
            const float* xp = xb + qr;
#pragma unroll 2
            for (int j = 0; j < 8; ++j) {
                int c = qg * 32 + j * 4;
                f32x4 v;
                v[0] = xp[(size_t)(c0 + c + 0) * HW_];
                v[1] = xp[(size_t)(c0 + c + 1) * HW_];
                v[2] = xp[(size_t)(c0 + c + 2) * HW_];
                v[3] = xp[(size_t)(c0 + c + 3) * HW_];
                *(f32x4*)&qs[qr * QS + c] = v;
            }
        }
        __syncthreads();
#pragma unroll
        for (int pp = 0; pp < 2; ++pp) {
            const int row = (t + 256 * pp) >> 4;
            const float4* mp = (const float4*)(mempool + (size_t)cnd[pp] * C_ + c0);
            const f32x4* qrow = (const f32x4*)&qs[row * QS];
            float a = racc[pp];
#pragma unroll 8
            for (int u = 0; u < 64; ++u) {
                f32x4 q4 = qrow[u];
                float4 m4 = mp[u];
                a = fmaf(q4[0], m4.x, a);
                a = fmaf(q4[1], m4.y, a);
                a = fmaf(q4[2], m4.z, a);
                a = fmaf(q4[3], m4.w, a);
            }
            racc[pp] = a;
        }
    }
    refv[t] = racc[0];
    refv[t + 256] = racc[1];
    __syncthreads();

    // ---- leader: exact top-8 of 16 + softmax ----
    if (t < 32) {
        const int row = t;
        float rv[16]; int ri[16];
#pragma unroll
        for (int s = 0; s < 16; ++s) { rv[s] = refv[row * 16 + s]; ri[s] = selidx[row * 16 + s]; }
        float wv8[8]; int wi8[8];
#pragma unroll
        for (int sel = 0; sel < 8; ++sel) {
            float vb = NEG_INF; int ib = 0x7fffffff; int sb = 0;
            for (int s = 0; s < 16; ++s) {
                if (rv[s] > vb || (rv[s] == vb && ri[s] < ib)) { vb = rv[s]; ib = ri[s]; sb = s; }
            }
            rv[sb] = NEG_INF;
            wv8[sel] = vb; wi8[sel] = ib;
        }
        const float mx = wv8[0];
        float e[8]; float sum = 0.f;
#pragma unroll
        for (int j = 0; j < 8; ++j) { e[j] = expf(wv8[j] - mx); sum += e[j]; }
        const float inv = 1.f / sum;
#pragma unroll
        for (int j = 0; j < 8; ++j) { w_lds[row * 8 + j] = e[j] * inv; i_lds[row * 8 + j] = wi8[j]; }
    }
    __syncthreads();

    // ---- combine: gathered mempool float4, coalesced-pair stores ----
    const int crow = t & 31;
    const int cw   = t >> 5;      // 0..7, 64 channels each
    float wreg[8]; int ireg[8];
#pragma unroll
    for (int j = 0; j < 8; ++j) { wreg[j] = w_lds[crow * 8 + j]; ireg[j] = i_lds[crow * 8 + j]; }
    float* outb = out + (size_t)b * C_ * HW_ + hw0 + crow;
#pragma unroll 2
    for (int cg = 0; cg < 16; ++cg) {
        const int c = cw * 64 + cg * 4;
        float o0 = 0.f, o1 = 0.f, o2 = 0.f, o3 = 0.f;
#pragma unroll
        for (int j = 0; j < 8; ++j) {
            const float4 mp4 = *(const float4*)&mempool[(size_t)ireg[j] * C_ + c];
            o0 = fmaf(wreg[j], mp4.x, o0);
            o1 = fmaf(wreg[j], mp4.y, o1);
            o2 = fmaf(wreg[j], mp4.z, o2);
            o3 = fmaf(wreg[j], mp4.w, o3);
        }
        outb[(size_t)(c + 0) * HW_] = o0;
        outb[(size_t)(c + 1) * HW_] = o1;
        outb[(size_t)(c + 2) * HW_] = o2;
        outb[(size_t)(c + 3) * HW_] = o3;
    }
}

extern "C" void kernel_launch(void* const* d_in, const int* in_sizes, int n_in,
                              void* d_out, int out_size, void* d_ws, size_t ws_size,
                              hipStream_t stream) {
    const float* x       = (const float*)d_in[0];
    const float* mempool = (const float*)d_in[1];
    unsigned short* membR = (unsigned short*)d_ws;                       // 2 MiB @0
    unsigned int*   gcand = (unsigned int*)((char*)d_ws + (4u << 20));   // 16 MiB @4M
    float* o = (float*)d_out;
    convk<<<dim3(512), dim3(256), 0, stream>>>(mempool, membR);
    gemmk<<<dim3(16, 256), dim3(256), 0, stream>>>(x, membR, gcand);
    mergek<<<dim3(1024), dim3(256), 0, stream>>>(x, mempool, gcand, o);
}

// Round 12
// 485.235 us; speedup vs baseline: 1.0153x; 1.0153x over previous
//
#include <hip/hip_runtime.h>

typedef __attribute__((ext_vector_type(4))) float f32x4;
typedef __attribute__((ext_vector_type(8))) short short8;

#define C_    512
#define HW_   1024
#define M_    2048
#define NEG_INF (-1e30f)

// ---- d_ws layout ----
// xbT   @0        : 32768*512*2 = 32 MiB   (x transposed, bf16, row-major [n][c])
// gcand @32 MiB   : 32768*128*4 = 16 MiB
// membR @48 MiB   : 2 MiB

__device__ __forceinline__ unsigned short f2bf(float f) {
    unsigned u = __builtin_bit_cast(unsigned, f);
    u += 0x7fffu + ((u >> 16) & 1u);     // RNE
    return (unsigned short)(u >> 16);
}
__device__ __forceinline__ float bf2f(unsigned short s) {
    return __builtin_bit_cast(float, (unsigned)s << 16);
}
__device__ __forceinline__ float pkval(unsigned u) {
    return __builtin_bit_cast(float, u & 0xFFFF0000u);
}
__device__ __forceinline__ void insert8(float v, int idx, float* sv, int* si) {
    sv[0] = v; si[0] = idx;
#pragma unroll
    for (int p = 0; p < 7; ++p) {
        if (sv[p] > sv[p + 1]) {
            float tv = sv[p]; sv[p] = sv[p + 1]; sv[p + 1] = tv;
            int   ti = si[p]; si[p] = si[p + 1]; si[p + 1] = ti;
        }
    }
}

// ---- repack mempool [2048][512] f32 -> membR bf16, kc-major (32ch chunks) ----
__global__ __launch_bounds__(256) void convk(const float* __restrict__ in,
                                             unsigned short* __restrict__ ob) {
    int gid = blockIdx.x * 256 + threadIdx.x;
    int m  = gid >> 6;
    int ug = gid & 63;
    const float4* p = (const float4*)(in + (size_t)m * C_ + ug * 8);
    float4 v0 = p[0], v1 = p[1];
    int4 o;
    o.x = (int)f2bf(v0.x) | ((int)f2bf(v0.y) << 16);
    o.y = (int)f2bf(v0.z) | ((int)f2bf(v0.w) << 16);
    o.z = (int)f2bf(v1.x) | ((int)f2bf(v1.y) << 16);
    o.w = (int)f2bf(v1.z) | ((int)f2bf(v1.w) << 16);
    int kc = ug >> 2, u = ug & 3;
    *(int4*)((char*)ob + (size_t)kc * 131072 + m * 64 + (u << 4)) = o;
}

// ---- transpose x [32][512][1024] f32 -> xbT [32768][512] bf16 ----
__global__ __launch_bounds__(256) void xconvk(const float* __restrict__ x,
                                              unsigned short* __restrict__ xbT) {
    __shared__ unsigned short tile[32 * 520];   // [hw][520] (512 + 8 pad)
    const int t   = threadIdx.x;
    const int hw0 = blockIdx.x * 32;
    const int b   = blockIdx.y;
    const float* xb = x + (size_t)b * C_ * HW_ + hw0;
    {
        const int cl = t >> 3, hwq = t & 7;
#pragma unroll 4
        for (int p = 0; p < 16; ++p) {
            int c = p * 32 + cl;
            float4 v = *(const float4*)(xb + (size_t)c * HW_ + hwq * 4);
#pragma unroll
            for (int j = 0; j < 4; ++j)
                tile[(hwq * 4 + j) * 520 + c] = f2bf(j == 0 ? v.x : (j == 1 ? v.y : (j == 2 ? v.z : v.w)));
        }
    }
    __syncthreads();
    {
        const int row = t >> 3, seg = t & 7;
        const char* src = (const char*)tile + row * 1040 + seg * 128;
        char* dst = (char*)xbT + (((size_t)(b * HW_ + hw0 + row)) << 10) + seg * 128;
#pragma unroll
        for (int i = 0; i < 8; ++i)
            *(short8*)(dst + i * 16) = *(const short8*)(src + i * 16);
    }
}

// ---------------- kernel 2: barrier-free 128x128 GEMM + exact per-tile top-8 ----------------
#define K2_CAND  33792
#define K2_ARENA 41984

__global__ __launch_bounds__(256, 3) void gemmk(const unsigned short* __restrict__ xbT,
                                                const unsigned short* __restrict__ membR,
                                                unsigned int* __restrict__ gcand) {
    __shared__ __align__(16) char arena[K2_ARENA];
    unsigned short* att16 = (unsigned short*)arena;
    unsigned int*   candt = (unsigned int*)(arena + K2_CAND);

    const int t   = threadIdx.x;
    const int l   = t & 63;
    const int w   = t >> 6;
    const int hi  = l >> 4;
    const int l15 = l & 15;
    const int colTile = blockIdx.x;       // 0..15
    const int rowTile = blockIdx.y;       // 0..255
    const int n0  = rowTile * 128;

    const char* abase = (const char*)xbT + (((size_t)(n0 + w * 32 + l15)) << 10) + (hi << 4);
    const char* bbase = (const char*)membR + colTile * 8192 + l15 * 64 + hi * 16;

    short8 aq0 = *(const short8*)abase;
    short8 aq1 = *(const short8*)(abase + 16384);
    short8 bq[8];
#pragma unroll
    for (int itf = 0; itf < 8; ++itf) bq[itf] = *(const short8*)(bbase + itf * 1024);

    f32x4 acc[2][8];
#pragma unroll
    for (int rf = 0; rf < 2; ++rf)
#pragma unroll
        for (int itf = 0; itf < 8; ++itf) acc[rf][itf] = (f32x4)0.f;

#pragma unroll 2
    for (int kc = 0; kc < 16; ++kc) {
        int kn = (kc + 1 < 16) ? kc + 1 : 15;
        short8 an0 = *(const short8*)(abase + kn * 64);
        short8 an1 = *(const short8*)(abase + 16384 + kn * 64);
        short8 bn[8];
        const char* pb = bbase + (size_t)kn * 131072;
#pragma unroll
        for (int itf = 0; itf < 8; ++itf) bn[itf] = *(const short8*)(pb + itf * 1024);
#pragma unroll
        for (int itf = 0; itf < 8; ++itf) {
            acc[0][itf] = __builtin_amdgcn_mfma_f32_16x16x32_bf16(aq0, bq[itf], acc[0][itf], 0, 0, 0);
            acc[1][itf] = __builtin_amdgcn_mfma_f32_16x16x32_bf16(aq1, bq[itf], acc[1][itf], 0, 0, 0);
        }
        aq0 = an0; aq1 = an1;
#pragma unroll
        for (int itf = 0; itf < 8; ++itf) bq[itf] = bn[itf];
    }

    // ---- dump att bf16 [128][132] ----
#pragma unroll
    for (int rf = 0; rf < 2; ++rf)
#pragma unroll
        for (int itf = 0; itf < 8; ++itf) {
            int col = itf * 16 + l15;
#pragma unroll
            for (int reg = 0; reg < 4; ++reg) {
                int row = w * 32 + rf * 16 + hi * 4 + reg;
                att16[row * 132 + col] = f2bf(acc[rf][itf][reg]);
            }
        }
    __syncthreads();

    // ---- scan: 2 threads/row, 64 items each ----
    const int sr = t >> 1, hf = t & 1;
    float sv[8]; int si[8];
#pragma unroll
    for (int p = 0; p < 8; ++p) { sv[p] = NEG_INF; si[p] = 0x7fffffff; }
    {
        const unsigned short* arow = att16 + sr * 132 + hf * 64;
#pragma unroll
        for (int v = 0; v < 8; ++v) {
            short8 pv = *(const short8*)(arow + v * 8);
            float f[8];
#pragma unroll
            for (int e = 0; e < 8; ++e) f[e] = bf2f((unsigned short)pv[e]);
            float m01 = fmaxf(f[0], f[1]), m23 = fmaxf(f[2], f[3]);
            float m45 = fmaxf(f[4], f[5]), m67 = fmaxf(f[6], f[7]);
            float vmax = fmaxf(fmaxf(m01, m23), fmaxf(m45, m67));
            if (vmax > sv[0]) {
#pragma unroll
                for (int e = 0; e < 8; ++e)
                    if (f[e] > sv[0]) insert8(f[e], hf * 64 + v * 8 + e, sv, si);
            }
        }
    }
    __syncthreads();
#pragma unroll
    for (int p = 0; p < 8; ++p)
        candt[(sr * 2 + hf) * 8 + p] =
            (__builtin_bit_cast(unsigned, sv[p]) & 0xFFFF0000u) |
            (unsigned)(colTile * 128 + si[p]);
    __syncthreads();

    // ---- merge 2 sorted-8 lists -> exact tile top-8 -> gcand ----
    if (t < 128) {
        const unsigned* c0 = candt + (t * 2 + 0) * 8;
        const unsigned* c1 = candt + (t * 2 + 1) * 8;
        int p0 = 7, p1 = 7;
        unsigned res[8];
#pragma unroll
        for (int s = 0; s < 8; ++s) {
            unsigned u0 = c0[p0 < 0 ? 0 : p0], u1 = c1[p1 < 0 ? 0 : p1];
            float v0 = (p0 >= 0) ? pkval(u0) : NEG_INF;
            float v1 = (p1 >= 0) ? pkval(u1) : NEG_INF;
            bool take0 = (v0 > v1) || (v0 == v1 && (int)(u0 & 0xFFFFu) < (int)(u1 & 0xFFFFu));
            if (p1 < 0) take0 = true;
            if (p0 < 0) take0 = false;
            if (take0) { res[s] = u0; --p0; } else { res[s] = u1; --p1; }
        }
        unsigned int* gp = gcand + (size_t)(n0 + t) * 128 + colTile * 8;
        *(uint4*)gp       = make_uint4(res[0], res[1], res[2], res[3]);
        *(uint4*)(gp + 4) = make_uint4(res[4], res[5], res[6], res[7]);
    }
}

// ---------------- kernel 3: merge -> top-16 -> SERIAL fp32 refine -> combine ----------------
#define QS 260
#define SEL_BASE 33792
#define RFV_BASE 35840
#define WL_BASE  37888
#define IL_BASE  38912
#define K3_ARENA 39936
#define NCAND 16

__global__ __launch_bounds__(256, 4) void mergek(const float* __restrict__ x,
                                                 const float* __restrict__ mempool,
                                                 const unsigned int* __restrict__ gcand,
                                                 float* __restrict__ out) {
    __shared__ __align__(16) char arena[K3_ARENA];
    float* candv  = (float*)arena;                   // [32][33]
    int*   candi  = (int*)(arena + 4224);            // [32][33]
    float* qs     = (float*)arena;                   // [32][260] overlay
    float* ot     = (float*)arena;                   // [256][33] overlay
    int*   selidx = (int*)(arena + SEL_BASE);        // [32][16]
    float* refv   = (float*)(arena + RFV_BASE);      // [32][16]
    float* w_lds  = (float*)(arena + WL_BASE);       // [32][8]
    int*   i_lds  = (int*)(arena + IL_BASE);         // [32][8]

    const int t   = threadIdx.x;
    const int n0  = blockIdx.x * 32;
    const int b   = n0 >> 10;
    const int hw0 = n0 & 1023;
    const float* xb = x + (size_t)b * C_ * HW_ + hw0;

    // ---- scan 128 candidates/row: 4 threads/row x 32 ----
    const int srow = t >> 2, stq = t & 3;
    float sv[8]; int si[8];
#pragma unroll
    for (int p = 0; p < 8; ++p) { sv[p] = NEG_INF; si[p] = 0x7fffffff; }
    if (t < 128) {
        const unsigned int* gc = gcand + (size_t)(n0 + srow) * 128 + stq * 32;
#pragma unroll 4
        for (int j = 0; j < 32; ++j) {
            unsigned u = gc[j];
            float v = pkval(u);
            if (v > sv[0]) insert8(v, (int)(u & 0xFFFFu), sv, si);
        }
#pragma unroll
        for (int p = 0; p < 8; ++p) {
            candv[srow * 33 + stq * 8 + p] = sv[p];
            candi[srow * 33 + stq * 8 + p] = si[p];
        }
    }
    __syncthreads();

    // ---- leader: 4-way merge -> approx top-16 ----
    if (t < 32) {
        const int row = t;
        int pos[4] = {7, 7, 7, 7};
        for (int s = 0; s < NCAND; ++s) {
            float vb = NEG_INF; int ib = 0x7fffffff; int qb = 0;
#pragma unroll
            for (int q = 0; q < 4; ++q) {
                if (pos[q] >= 0) {
                    float v = candv[row * 33 + q * 8 + pos[q]];
                    int  ii = candi[row * 33 + q * 8 + pos[q]];
                    if (v > vb || (v == vb && ii < ib)) { vb = v; ib = ii; qb = q; }
                }
            }
            selidx[row * NCAND + s] = ib;
#pragma unroll
            for (int q = 0; q < 4; ++q) if (q == qb) --pos[q];
        }
    }
    __syncthreads();

    // ---- exact fp32 refine: PER-THREAD SERIAL channel-order sum (proven R6-R10;
    //      summation order is load-bearing for near-tie rows — do not reorder) ----
    int cnd[2];
    cnd[0] = selidx[t];
    cnd[1] = selidx[t + 256];
    float racc[2] = {0.f, 0.f};
#pragma unroll
    for (int ch = 0; ch < 2; ++ch) {
        const int c0 = ch * 256;
        __syncthreads();               // candv dead / prior qs reads done
        {
            const int qr = t & 31, qg = t >> 5;
            const float* xp = xb + qr;
#pragma unroll 2
            for (int j = 0; j < 8; ++j) {
                int c = qg * 32 + j * 4;
                f32x4 v;
                v[0] = xp[(size_t)(c0 + c + 0) * HW_];
                v[1] = xp[(size_t)(c0 + c + 1) * HW_];
                v[2] = xp[(size_t)(c0 + c + 2) * HW_];
                v[3] = xp[(size_t)(c0 + c + 3) * HW_];
                *(f32x4*)&qs[qr * QS + c] = v;
            }
        }
        __syncthreads();
#pragma unroll
        for (int pp = 0; pp < 2; ++pp) {
            const int row = (t + 256 * pp) >> 4;
            const float4* mp = (const float4*)(mempool + (size_t)cnd[pp] * C_ + c0);
            const f32x4* qrow = (const f32x4*)&qs[row * QS];
            float a = racc[pp];
#pragma unroll 8
            for (int u = 0; u < 64; ++u) {
                f32x4 q4 = qrow[u];
                float4 m4 = mp[u];
                a = fmaf(q4[0], m4.x, a);
                a = fmaf(q4[1], m4.y, a);
                a = fmaf(q4[2], m4.z, a);
                a = fmaf(q4[3], m4.w, a);
            }
            racc[pp] = a;
        }
    }
    refv[t] = racc[0];
    refv[t + 256] = racc[1];
    __syncthreads();

    // ---- leader: exact top-8 of 16 + softmax ----
    if (t < 32) {
        const int row = t;
        float rv[16]; int ri[16];
#pragma unroll
        for (int s = 0; s < 16; ++s) { rv[s] = refv[row * 16 + s]; ri[s] = selidx[row * 16 + s]; }
        float wv8[8]; int wi8[8];
#pragma unroll
        for (int sel = 0; sel < 8; ++sel) {
            float vb = NEG_INF; int ib = 0x7fffffff; int sb = 0;
            for (int s = 0; s < 16; ++s) {
                if (rv[s] > vb || (rv[s] == vb && ri[s] < ib)) { vb = rv[s]; ib = ri[s]; sb = s; }
            }
            rv[sb] = NEG_INF;
            wv8[sel] = vb; wi8[sel] = ib;
        }
        const float mx = wv8[0];
        float e[8]; float sum = 0.f;
#pragma unroll
        for (int j = 0; j < 8; ++j) { e[j] = expf(wv8[j] - mx); sum += e[j]; }
        const float inv = 1.f / sum;
#pragma unroll
        for (int j = 0; j < 8; ++j) { w_lds[row * 8 + j] = e[j] * inv; i_lds[row * 8 + j] = wi8[j]; }
    }
    __syncthreads();

    // ---- combine: 16-lane group per row, contiguous mempool reads, LDS transpose
    //      (per-element fp32 op order identical to proven direct version) ----
    const int lg = t & 15;
    const int g  = t >> 4;    // 0..15
#pragma unroll
    for (int half = 0; half < 2; ++half) {
#pragma unroll
        for (int rp = 0; rp < 2; ++rp) {
            const int row = g + rp * 16;
            float wreg[8]; int ireg[8];
#pragma unroll
            for (int j = 0; j < 8; ++j) { wreg[j] = w_lds[row * 8 + j]; ireg[j] = i_lds[row * 8 + j]; }
            f32x4 o[4];
#pragma unroll
            for (int it = 0; it < 4; ++it) o[it] = (f32x4)0.f;
#pragma unroll
            for (int j = 0; j < 8; ++j) {
                const float4* mp = (const float4*)(mempool + (size_t)ireg[j] * C_ + half * 256) + lg;
#pragma unroll
                for (int it = 0; it < 4; ++it) {
                    float4 m4 = mp[it * 16];
                    o[it][0] = fmaf(wreg[j], m4.x, o[it][0]);
                    o[it][1] = fmaf(wreg[j], m4.y, o[it][1]);
                    o[it][2] = fmaf(wreg[j], m4.z, o[it][2]);
                    o[it][3] = fmaf(wreg[j], m4.w, o[it][3]);
                }
            }
#pragma unroll
            for (int it = 0; it < 4; ++it)
#pragma unroll
                for (int i = 0; i < 4; ++i)
                    ot[(it * 64 + lg * 4 + i) * 33 + row] = o[it][i];
        }
        __syncthreads();
        {
            const int r = t & 31, cb = t >> 5;
            float* op = out + (size_t)b * C_ * HW_ + (size_t)(half * 256) * HW_ + hw0 + r;
#pragma unroll 4
            for (int cc = 0; cc < 32; ++cc) {
                int c = cb * 32 + cc;
                op[(size_t)c * HW_] = ot[c * 33 + r];
            }
        }
        __syncthreads();
    }
}

extern "C" void kernel_launch(void* const* d_in, const int* in_sizes, int n_in,
                              void* d_out, int out_size, void* d_ws, size_t ws_size,
                              hipStream_t stream) {
    const float* x       = (const float*)d_in[0];
    const float* mempool = (const float*)d_in[1];
    unsigned short* xbT   = (unsigned short*)d_ws;                        // 32 MiB @0
    unsigned int*   gcand = (unsigned int*)((char*)d_ws + (32u << 20));   // 16 MiB @32M
    unsigned short* membR = (unsigned short*)((char*)d_ws + (48u << 20)); //  2 MiB @48M
    float* o = (float*)d_out;
    xconvk<<<dim3(32, 32), dim3(256), 0, stream>>>(x, xbT);
    convk<<<dim3(512), dim3(256), 0, stream>>>(mempool, membR);
    gemmk<<<dim3(16, 256), dim3(256), 0, stream>>>(xbT, membR, gcand);
    mergek<<<dim3(1024), dim3(256), 0, stream>>>(x, mempool, gcand, o);
}

// Round 13
// 412.123 us; speedup vs baseline: 1.1954x; 1.1774x over previous
//
#include <hip/hip_runtime.h>

typedef __attribute__((ext_vector_type(4))) float f32x4;
typedef __attribute__((ext_vector_type(8))) short short8;

#define C_    512
#define HW_   1024
#define M_    2048
#define NEG_INF (-1e30f)

// ---- d_ws layout ----
// xbT   @0        : 32 MiB  (x transposed, bf16, row-major [n][c])
// gcand @32 MiB   : 32768*64*4 = 8 MiB
// membR @48 MiB   : 2 MiB (bf16, kc-major)

__device__ __forceinline__ unsigned short f2bf(float f) {
    unsigned u = __builtin_bit_cast(unsigned, f);
    u += 0x7fffu + ((u >> 16) & 1u);     // RNE
    return (unsigned short)(u >> 16);
}
__device__ __forceinline__ float bf2f(unsigned short s) {
    return __builtin_bit_cast(float, (unsigned)s << 16);
}
__device__ __forceinline__ float pkval(unsigned u) {
    return __builtin_bit_cast(float, u & 0xFFFF0000u);
}
__device__ __forceinline__ void insert8(float v, int idx, float* sv, int* si) {
    sv[0] = v; si[0] = idx;
#pragma unroll
    for (int p = 0; p < 7; ++p) {
        if (sv[p] > sv[p + 1]) {
            float tv = sv[p]; sv[p] = sv[p + 1]; sv[p + 1] = tv;
            int   ti = si[p]; si[p] = si[p + 1]; si[p + 1] = ti;
        }
    }
}

// ---- repack mempool [2048][512] f32 -> membR bf16, kc-major (32ch chunks) ----
__global__ __launch_bounds__(256) void convk(const float* __restrict__ in,
                                             unsigned short* __restrict__ ob) {
    int gid = blockIdx.x * 256 + threadIdx.x;
    int m  = gid >> 6;
    int ug = gid & 63;
    const float4* p = (const float4*)(in + (size_t)m * C_ + ug * 8);
    float4 v0 = p[0], v1 = p[1];
    int4 o;
    o.x = (int)f2bf(v0.x) | ((int)f2bf(v0.y) << 16);
    o.y = (int)f2bf(v0.z) | ((int)f2bf(v0.w) << 16);
    o.z = (int)f2bf(v1.x) | ((int)f2bf(v1.y) << 16);
    o.w = (int)f2bf(v1.z) | ((int)f2bf(v1.w) << 16);
    int kc = ug >> 2, u = ug & 3;
    *(int4*)((char*)ob + (size_t)kc * 131072 + m * 64 + (u << 4)) = o;
}

// ---- transpose x [32][512][1024] f32 -> xbT [32768][512] bf16 ----
__global__ __launch_bounds__(256) void xconvk(const float* __restrict__ x,
                                              unsigned short* __restrict__ xbT) {
    __shared__ unsigned short tile[32 * 520];
    const int t   = threadIdx.x;
    const int hw0 = blockIdx.x * 32;
    const int b   = blockIdx.y;
    const float* xb = x + (size_t)b * C_ * HW_ + hw0;
    {
        const int cl = t >> 3, hwq = t & 7;
#pragma unroll 4
        for (int p = 0; p < 16; ++p) {
            int c = p * 32 + cl;
            float4 v = *(const float4*)(xb + (size_t)c * HW_ + hwq * 4);
#pragma unroll
            for (int j = 0; j < 4; ++j)
                tile[(hwq * 4 + j) * 520 + c] = f2bf(j == 0 ? v.x : (j == 1 ? v.y : (j == 2 ? v.z : v.w)));
        }
    }
    __syncthreads();
    {
        const int row = t >> 3, seg = t & 7;
        const char* src = (const char*)tile + row * 1040 + seg * 128;
        char* dst = (char*)xbT + (((size_t)(b * HW_ + hw0 + row)) << 10) + seg * 128;
#pragma unroll
        for (int i = 0; i < 8; ++i)
            *(short8*)(dst + i * 16) = *(const short8*)(src + i * 16);
    }
}

// ------- kernel 2: 64x256 tile; A in LDS (1x), wave-partitioned B (1x); top-8/tile -------
#define K2_ARENA 65536                 // A bf16 [64][1024B] swizzled; post-GEMM overlay:
#define CT_BASE  33792                 //   att16 [64][264] @0 (33792B) + candt @33792 (8KB)

__global__ __launch_bounds__(256, 2) void gemmk(const unsigned short* __restrict__ xbT,
                                                const unsigned short* __restrict__ membR,
                                                unsigned int* __restrict__ gcand) {
    __shared__ __align__(16) char arena[K2_ARENA];
    unsigned short* att16 = (unsigned short*)arena;
    unsigned int*   candt = (unsigned int*)(arena + CT_BASE);

    const int t   = threadIdx.x;
    const int l   = t & 63;
    const int w   = t >> 6;
    const int hi  = l >> 4;
    const int l15 = l & 15;
    const int colTile = blockIdx.x;       // 0..7  (256 items)
    const int rowTile = blockIdx.y;       // 0..511 (64 rows)
    const int n0 = rowTile * 64;
    const int m0 = colTile * 256;

    // B frag base: item = m0 + w*64 + itf*16 + l15 (waves partition items)
    const char* bbase = (const char*)membR + (size_t)(m0 + w * 64 + l15) * 64 + hi * 16;

    // prefetch B kc=0 (before barrier — hides under A staging)
    short8 bq[4];
#pragma unroll
    for (int itf = 0; itf < 4; ++itf) bq[itf] = *(const short8*)(bbase + itf * 1024);

    // ---- stage A once: wave w loads row w*16+i fully coalesced (1KB/instr), XOR-swz ----
#pragma unroll 4
    for (int i = 0; i < 16; ++i) {
        int row = w * 16 + i;
        short8 v = *(const short8*)((const char*)xbT + (((size_t)(n0 + row)) << 10) + l * 16);
        *(short8*)(arena + row * 1024 + ((l * 16) ^ ((row & 7) << 4))) = v;
    }
    __syncthreads();

    const int aswz = (l15 & 7) << 4;
    f32x4 acc[4][4];
#pragma unroll
    for (int rf = 0; rf < 4; ++rf)
#pragma unroll
        for (int itf = 0; itf < 4; ++itf) acc[rf][itf] = (f32x4)0.f;

#pragma unroll 2
    for (int kc = 0; kc < 16; ++kc) {
        int kn = (kc + 1 < 16) ? kc + 1 : 15;
        short8 bn[4];
        const char* pb = bbase + (size_t)kn * 131072;
#pragma unroll
        for (int itf = 0; itf < 4; ++itf) bn[itf] = *(const short8*)(pb + itf * 1024);
        short8 af[4];
#pragma unroll
        for (int rf = 0; rf < 4; ++rf)
            af[rf] = *(const short8*)(arena + (rf * 16 + l15) * 1024 + ((kc * 64 + hi * 16) ^ aswz));
#pragma unroll
        for (int rf = 0; rf < 4; ++rf)
#pragma unroll
            for (int itf = 0; itf < 4; ++itf)
                acc[rf][itf] = __builtin_amdgcn_mfma_f32_16x16x32_bf16(af[rf], bq[itf], acc[rf][itf], 0, 0, 0);
#pragma unroll
        for (int itf = 0; itf < 4; ++itf) bq[itf] = bn[itf];
    }
    __syncthreads();   // all waves' A ds_reads done before att overlays A

    // ---- dump att bf16 [64][264] ----
#pragma unroll
    for (int rf = 0; rf < 4; ++rf)
#pragma unroll
        for (int itf = 0; itf < 4; ++itf) {
            int col = w * 64 + itf * 16 + l15;
#pragma unroll
            for (int reg = 0; reg < 4; ++reg)
                att16[(rf * 16 + hi * 4 + reg) * 264 + col] = f2bf(acc[rf][itf][reg]);
        }
    __syncthreads();

    // ---- scan: 4 threads/row, 64 items each (proven vectorized + prune) ----
    const int srow = t >> 2, stq = t & 3;
    float sv[8]; int si[8];
#pragma unroll
    for (int p = 0; p < 8; ++p) { sv[p] = NEG_INF; si[p] = 0x7fffffff; }
    {
        const unsigned short* arow = att16 + srow * 264;
#pragma unroll
        for (int v = 0; v < 8; ++v) {
            short8 pv = *(const short8*)(arow + stq * 8 + v * 32);
            float f[8];
#pragma unroll
            for (int e = 0; e < 8; ++e) f[e] = bf2f((unsigned short)pv[e]);
            float m01 = fmaxf(f[0], f[1]), m23 = fmaxf(f[2], f[3]);
            float m45 = fmaxf(f[4], f[5]), m67 = fmaxf(f[6], f[7]);
            float vmax = fmaxf(fmaxf(m01, m23), fmaxf(m45, m67));
            if (vmax > sv[0]) {
#pragma unroll
                for (int e = 0; e < 8; ++e)
                    if (f[e] > sv[0]) insert8(f[e], m0 + stq * 8 + v * 32 + e, sv, si);
            }
        }
    }
    __syncthreads();
#pragma unroll
    for (int p = 0; p < 8; ++p)
        candt[(srow * 4 + stq) * 8 + p] =
            (__builtin_bit_cast(unsigned, sv[p]) & 0xFFFF0000u) | (unsigned)si[p];
    __syncthreads();

    // ---- leader per row: 4-way merge of sorted-8 -> exact tile top-8 -> gcand ----
    if (t < 64) {
        int pos[4] = {7, 7, 7, 7};
        unsigned res[8];
#pragma unroll
        for (int s = 0; s < 8; ++s) {
            float vb = NEG_INF; int ib = 0x7fffffff; int qb = 0;
#pragma unroll
            for (int q = 0; q < 4; ++q) {
                if (pos[q] >= 0) {
                    unsigned u = candt[(t * 4 + q) * 8 + pos[q]];
                    float v = pkval(u);
                    int  ii = (int)(u & 0xFFFFu);
                    if (v > vb || (v == vb && ii < ib)) { vb = v; ib = ii; qb = q; }
                }
            }
            res[s] = candt[(t * 4 + qb) * 8 + pos[qb]];
            --pos[qb];
        }
        unsigned int* gp = gcand + (size_t)(n0 + t) * 64 + colTile * 8;
        *(uint4*)gp       = make_uint4(res[0], res[1], res[2], res[3]);
        *(uint4*)(gp + 4) = make_uint4(res[4], res[5], res[6], res[7]);
    }
}

// ---------------- kernel 3: merge -> top-16 -> SERIAL fp32 refine -> combine ----------------
#define QS 260
#define SEL_BASE 33792
#define RFV_BASE 35840
#define WL_BASE  37888
#define IL_BASE  38912
#define K3_ARENA 39936
#define NCAND 16

__global__ __launch_bounds__(256, 4) void mergek(const float* __restrict__ x,
                                                 const float* __restrict__ mempool,
                                                 const unsigned int* __restrict__ gcand,
                                                 float* __restrict__ out) {
    __shared__ __align__(16) char arena[K3_ARENA];
    float* candv  = (float*)arena;                   // [32][33]
    int*   candi  = (int*)(arena + 4224);            // [32][33]
    float* qs     = (float*)arena;                   // [32][260] overlay
    float* ot     = (float*)arena;                   // [256][33] overlay
    int*   selidx = (int*)(arena + SEL_BASE);        // [32][16]
    float* refv   = (float*)(arena + RFV_BASE);      // [32][16]
    float* w_lds  = (float*)(arena + WL_BASE);       // [32][8]
    int*   i_lds  = (int*)(arena + IL_BASE);         // [32][8]

    const int t   = threadIdx.x;
    const int n0  = blockIdx.x * 32;
    const int b   = n0 >> 10;
    const int hw0 = n0 & 1023;
    const float* xb = x + (size_t)b * C_ * HW_ + hw0;

    // ---- scan 64 candidates/row: 4 threads/row x 16 ----
    const int srow = t >> 2, stq = t & 3;
    float sv[8]; int si[8];
#pragma unroll
    for (int p = 0; p < 8; ++p) { sv[p] = NEG_INF; si[p] = 0x7fffffff; }
    if (t < 128) {
        const unsigned int* gc = gcand + (size_t)(n0 + srow) * 64 + stq * 16;
#pragma unroll 4
        for (int j = 0; j < 16; ++j) {
            unsigned u = gc[j];
            float v = pkval(u);
            if (v > sv[0]) insert8(v, (int)(u & 0xFFFFu), sv, si);
        }
#pragma unroll
        for (int p = 0; p < 8; ++p) {
            candv[srow * 33 + stq * 8 + p] = sv[p];
            candi[srow * 33 + stq * 8 + p] = si[p];
        }
    }
    __syncthreads();

    // ---- leader: 4-way merge -> approx top-16 ----
    if (t < 32) {
        const int row = t;
        int pos[4] = {7, 7, 7, 7};
        for (int s = 0; s < NCAND; ++s) {
            float vb = NEG_INF; int ib = 0x7fffffff; int qb = 0;
#pragma unroll
            for (int q = 0; q < 4; ++q) {
                if (pos[q] >= 0) {
                    float v = candv[row * 33 + q * 8 + pos[q]];
                    int  ii = candi[row * 33 + q * 8 + pos[q]];
                    if (v > vb || (v == vb && ii < ib)) { vb = v; ib = ii; qb = q; }
                }
            }
            selidx[row * NCAND + s] = ib;
#pragma unroll
            for (int q = 0; q < 4; ++q) if (q == qb) --pos[q];
        }
    }
    __syncthreads();

    // ---- exact fp32 refine: PER-THREAD SERIAL channel-order sum (order load-bearing) ----
    int cnd[2];
    cnd[0] = selidx[t];
    cnd[1] = selidx[t + 256];
    float racc[2] = {0.f, 0.f};
#pragma unroll
    for (int ch = 0; ch < 2; ++ch) {
        const int c0 = ch * 256;
        __syncthreads();
        {
            const int qr = t & 31, qg = t >> 5;
            const float* xp = xb + qr;
#pragma unroll 2
            for (int j = 0; j < 8; ++j) {
                int c = qg * 32 + j * 4;
                f32x4 v;
                v[0] = xp[(size_t)(c0 + c + 0) * HW_];
                v[1] = xp[(size_t)(c0 + c + 1) * HW_];
                v[2] = xp[(size_t)(c0 + c + 2) * HW_];
                v[3] = xp[(size_t)(c0 + c + 3) * HW_];
                *(f32x4*)&qs[qr * QS + c] = v;
            }
        }
        __syncthreads();
#pragma unroll
        for (int pp = 0; pp < 2; ++pp) {
            const int row = (t + 256 * pp) >> 4;
            const float4* mp = (const float4*)(mempool + (size_t)cnd[pp] * C_ + c0);
            const f32x4* qrow = (const f32x4*)&qs[row * QS];
            float a = racc[pp];
#pragma unroll 8
            for (int u = 0; u < 64; ++u) {
                f32x4 q4 = qrow[u];
                float4 m4 = mp[u];
                a = fmaf(q4[0], m4.x, a);
                a = fmaf(q4[1], m4.y, a);
                a = fmaf(q4[2], m4.z, a);
                a = fmaf(q4[3], m4.w, a);
            }
            racc[pp] = a;
        }
    }
    refv[t] = racc[0];
    refv[t + 256] = racc[1];
    __syncthreads();

    // ---- leader: exact top-8 of 16 + softmax ----
    if (t < 32) {
        const int row = t;
        float rv[16]; int ri[16];
#pragma unroll
        for (int s = 0; s < 16; ++s) { rv[s] = refv[row * 16 + s]; ri[s] = selidx[row * 16 + s]; }
        float wv8[8]; int wi8[8];
#pragma unroll
        for (int sel = 0; sel < 8; ++sel) {
            float vb = NEG_INF; int ib = 0x7fffffff; int sb = 0;
            for (int s = 0; s < 16; ++s) {
                if (rv[s] > vb || (rv[s] == vb && ri[s] < ib)) { vb = rv[s]; ib = ri[s]; sb = s; }
            }
            rv[sb] = NEG_INF;
            wv8[sel] = vb; wi8[sel] = ib;
        }
        const float mx = wv8[0];
        float e[8]; float sum = 0.f;
#pragma unroll
        for (int j = 0; j < 8; ++j) { e[j] = expf(wv8[j] - mx); sum += e[j]; }
        const float inv = 1.f / sum;
#pragma unroll
        for (int j = 0; j < 8; ++j) { w_lds[row * 8 + j] = e[j] * inv; i_lds[row * 8 + j] = wi8[j]; }
    }
    __syncthreads();

    // ---- combine: 16-lane group per row, contiguous mempool reads, LDS transpose ----
    const int lg = t & 15;
    const int g  = t >> 4;
#pragma unroll
    for (int half = 0; half < 2; ++half) {
#pragma unroll
        for (int rp = 0; rp < 2; ++rp) {
            const int row = g + rp * 16;
            float wreg[8]; int ireg[8];
#pragma unroll
            for (int j = 0; j < 8; ++j) { wreg[j] = w_lds[row * 8 + j]; ireg[j] = i_lds[row * 8 + j]; }
            f32x4 o[4];
#pragma unroll
            for (int it = 0; it < 4; ++it) o[it] = (f32x4)0.f;
#pragma unroll
            for (int j = 0; j < 8; ++j) {
                const float4* mp = (const float4*)(mempool + (size_t)ireg[j] * C_ + half * 256) + lg;
#pragma unroll
                for (int it = 0; it < 4; ++it) {
                    float4 m4 = mp[it * 16];
                    o[it][0] = fmaf(wreg[j], m4.x, o[it][0]);
                    o[it][1] = fmaf(wreg[j], m4.y, o[it][1]);
                    o[it][2] = fmaf(wreg[j], m4.z, o[it][2]);
                    o[it][3] = fmaf(wreg[j], m4.w, o[it][3]);
                }
            }
#pragma unroll
            for (int it = 0; it < 4; ++it)
#pragma unroll
                for (int i = 0; i < 4; ++i)
                    ot[(it * 64 + lg * 4 + i) * 33 + row] = o[it][i];
        }
        __syncthreads();
        {
            const int r = t & 31, cb = t >> 5;
            float* op = out + (size_t)b * C_ * HW_ + (size_t)(half * 256) * HW_ + hw0 + r;
#pragma unroll 4
            for (int cc = 0; cc < 32; ++cc) {
                int c = cb * 32 + cc;
                op[(size_t)c * HW_] = ot[c * 33 + r];
            }
        }
        __syncthreads();
    }
}

extern "C" void kernel_launch(void* const* d_in, const int* in_sizes, int n_in,
                              void* d_out, int out_size, void* d_ws, size_t ws_size,
                              hipStream_t stream) {
    const float* x       = (const float*)d_in[0];
    const float* mempool = (const float*)d_in[1];
    unsigned short* xbT   = (unsigned short*)d_ws;                        // 32 MiB @0
    unsigned int*   gcand = (unsigned int*)((char*)d_ws + (32u << 20));   //  8 MiB @32M
    unsigned short* membR = (unsigned short*)((char*)d_ws + (48u << 20)); //  2 MiB @48M
    float* o = (float*)d_out;
    xconvk<<<dim3(32, 32), dim3(256), 0, stream>>>(x, xbT);
    convk<<<dim3(512), dim3(256), 0, stream>>>(mempool, membR);
    gemmk<<<dim3(8, 512), dim3(256), 0, stream>>>(xbT, membR, gcand);
    mergek<<<dim3(1024), dim3(256), 0, stream>>>(x, mempool, gcand, o);
}

// Round 14
// 356.737 us; speedup vs baseline: 1.3810x; 1.1553x over previous
//
#include <hip/hip_runtime.h>

typedef __attribute__((ext_vector_type(4))) float f32x4;
typedef __attribute__((ext_vector_type(8))) short short8;

#define C_    512
#define HW_   1024
#define M_    2048
#define NEG_INF (-1e30f)

// ---- d_ws layout ----
// xbT   @0        : 32 MiB  (x transposed, bf16, row-major [n][c])
// gcand @32 MiB   : 32768*64*4 = 8 MiB
// membR @48 MiB   : 2 MiB (bf16, kc-major)

__device__ __forceinline__ unsigned short f2bf(float f) {
    unsigned u = __builtin_bit_cast(unsigned, f);
    u += 0x7fffu + ((u >> 16) & 1u);     // RNE
    return (unsigned short)(u >> 16);
}
__device__ __forceinline__ float bf2f(unsigned short s) {
    return __builtin_bit_cast(float, (unsigned)s << 16);
}
__device__ __forceinline__ float pkval(unsigned u) {
    return __builtin_bit_cast(float, u & 0xFFFF0000u);
}
__device__ __forceinline__ void insert8(float v, int idx, float* sv, int* si) {
    sv[0] = v; si[0] = idx;
#pragma unroll
    for (int p = 0; p < 7; ++p) {
        if (sv[p] > sv[p + 1]) {
            float tv = sv[p]; sv[p] = sv[p + 1]; sv[p + 1] = tv;
            int   ti = si[p]; si[p] = si[p + 1]; si[p + 1] = ti;
        }
    }
}

// ---- repack mempool [2048][512] f32 -> membR bf16, kc-major (32ch chunks) ----
__global__ __launch_bounds__(256) void convk(const float* __restrict__ in,
                                             unsigned short* __restrict__ ob) {
    int gid = blockIdx.x * 256 + threadIdx.x;
    int m  = gid >> 6;
    int ug = gid & 63;
    const float4* p = (const float4*)(in + (size_t)m * C_ + ug * 8);
    float4 v0 = p[0], v1 = p[1];
    int4 o;
    o.x = (int)f2bf(v0.x) | ((int)f2bf(v0.y) << 16);
    o.y = (int)f2bf(v0.z) | ((int)f2bf(v0.w) << 16);
    o.z = (int)f2bf(v1.x) | ((int)f2bf(v1.y) << 16);
    o.w = (int)f2bf(v1.z) | ((int)f2bf(v1.w) << 16);
    int kc = ug >> 2, u = ug & 3;
    *(int4*)((char*)ob + (size_t)kc * 131072 + m * 64 + (u << 4)) = o;
}

// ---- transpose x [32][512][1024] f32 -> xbT [32768][512] bf16 ----
__global__ __launch_bounds__(256) void xconvk(const float* __restrict__ x,
                                              unsigned short* __restrict__ xbT) {
    __shared__ unsigned short tile[32 * 520];
    const int t   = threadIdx.x;
    const int hw0 = blockIdx.x * 32;
    const int b   = blockIdx.y;
    const float* xb = x + (size_t)b * C_ * HW_ + hw0;
    {
        const int cl = t >> 3, hwq = t & 7;
#pragma unroll 4
        for (int p = 0; p < 16; ++p) {
            int c = p * 32 + cl;
            float4 v = *(const float4*)(xb + (size_t)c * HW_ + hwq * 4);
#pragma unroll
            for (int j = 0; j < 4; ++j)
                tile[(hwq * 4 + j) * 520 + c] = f2bf(j == 0 ? v.x : (j == 1 ? v.y : (j == 2 ? v.z : v.w)));
        }
    }
    __syncthreads();
    {
        const int row = t >> 3, seg = t & 7;
        const char* src = (const char*)tile + row * 1040 + seg * 128;
        char* dst = (char*)xbT + (((size_t)(b * HW_ + hw0 + row)) << 10) + seg * 128;
#pragma unroll
        for (int i = 0; i < 8; ++i)
            *(short8*)(dst + i * 16) = *(const short8*)(src + i * 16);
    }
}

// ------- kernel 2: 64x256 tile; A half-staged in LDS (33KB arena, 4 blk/CU) -------
// arena overlays (in time): A [64][528B] (GEMM) -> att16 [64][264]u16 (dump/scan)
//                           -> candt [256][8]u32 @0 (post-scan)
#define K2_ARENA 33792

__global__ __launch_bounds__(256, 4) void gemmk(const unsigned short* __restrict__ xbT,
                                                const unsigned short* __restrict__ membR,
                                                unsigned int* __restrict__ gcand) {
    __shared__ __align__(16) char arena[K2_ARENA];
    unsigned short* att16 = (unsigned short*)arena;
    unsigned int*   candt = (unsigned int*)arena;    // overlays att16 after scan barrier

    const int t   = threadIdx.x;
    const int l   = t & 63;
    const int w   = t >> 6;
    const int hi  = l >> 4;
    const int l15 = l & 15;
    const int colTile = blockIdx.x;       // 0..7  (256 items)
    const int rowTile = blockIdx.y;       // 0..511 (64 rows)
    const int n0 = rowTile * 64;
    const int m0 = colTile * 256;

    // B frag base: item = m0 + w*64 + itf*16 + l15 (waves partition items)
    const char* bbase = (const char*)membR + (size_t)(m0 + w * 64 + l15) * 64 + hi * 16;

    // prefetch B step 0
    short8 bq[4];
#pragma unroll
    for (int itf = 0; itf < 4; ++itf) bq[itf] = *(const short8*)(bbase + itf * 1024);

    const int aswz = (l15 & 7) << 4;
    f32x4 acc[4][4];
#pragma unroll
    for (int rf = 0; rf < 4; ++rf)
#pragma unroll
        for (int itf = 0; itf < 4; ++itf) acc[rf][itf] = (f32x4)0.f;

    for (int h = 0; h < 2; ++h) {
        // ---- stage A half h: [64][528B], XOR-swizzled 16B units ----
#pragma unroll
        for (int j = 0; j < 8; ++j) {
            int row = w * 16 + j * 2 + (l >> 5);
            short8 v = *(const short8*)((const char*)xbT +
                        (((size_t)(n0 + row)) << 10) + h * 512 + (l & 31) * 16);
            *(short8*)(arena + row * 528 + (((l & 31) * 16) ^ ((row & 7) << 4))) = v;
        }
        __syncthreads();

#pragma unroll 2
        for (int kc = 0; kc < 8; ++kc) {
            int sn = h * 8 + kc + 1;
            if (sn > 15) sn = 15;
            short8 bn[4];
            const char* pb = bbase + (size_t)sn * 131072;
#pragma unroll
            for (int itf = 0; itf < 4; ++itf) bn[itf] = *(const short8*)(pb + itf * 1024);
            short8 af[4];
#pragma unroll
            for (int rf = 0; rf < 4; ++rf)
                af[rf] = *(const short8*)(arena + (rf * 16 + l15) * 528 +
                                          ((kc * 64 + hi * 16) ^ aswz));
#pragma unroll
            for (int rf = 0; rf < 4; ++rf)
#pragma unroll
                for (int itf = 0; itf < 4; ++itf)
                    acc[rf][itf] = __builtin_amdgcn_mfma_f32_16x16x32_bf16(af[rf], bq[itf], acc[rf][itf], 0, 0, 0);
#pragma unroll
            for (int itf = 0; itf < 4; ++itf) bq[itf] = bn[itf];
        }
        __syncthreads();   // A reads done before restage / att dump
    }

    // ---- dump att bf16 [64][264] (overlays A region) ----
#pragma unroll
    for (int rf = 0; rf < 4; ++rf)
#pragma unroll
        for (int itf = 0; itf < 4; ++itf) {
            int col = w * 64 + itf * 16 + l15;
#pragma unroll
            for (int reg = 0; reg < 4; ++reg)
                att16[(rf * 16 + hi * 4 + reg) * 264 + col] = f2bf(acc[rf][itf][reg]);
        }
    __syncthreads();

    // ---- scan: 4 threads/row, 64 items each (proven vectorized + prune) ----
    const int srow = t >> 2, stq = t & 3;
    float sv[8]; int si[8];
#pragma unroll
    for (int p = 0; p < 8; ++p) { sv[p] = NEG_INF; si[p] = 0x7fffffff; }
    {
        const unsigned short* arow = att16 + srow * 264;
#pragma unroll
        for (int v = 0; v < 8; ++v) {
            short8 pv = *(const short8*)(arow + stq * 8 + v * 32);
            float f[8];
#pragma unroll
            for (int e = 0; e < 8; ++e) f[e] = bf2f((unsigned short)pv[e]);
            float m01 = fmaxf(f[0], f[1]), m23 = fmaxf(f[2], f[3]);
            float m45 = fmaxf(f[4], f[5]), m67 = fmaxf(f[6], f[7]);
            float vmax = fmaxf(fmaxf(m01, m23), fmaxf(m45, m67));
            if (vmax > sv[0]) {
#pragma unroll
                for (int e = 0; e < 8; ++e)
                    if (f[e] > sv[0]) insert8(f[e], m0 + stq * 8 + v * 32 + e, sv, si);
            }
        }
    }
    __syncthreads();   // all scans done; att16 dead -> candt overlay
#pragma unroll
    for (int p = 0; p < 8; ++p)
        candt[(srow * 4 + stq) * 8 + p] =
            (__builtin_bit_cast(unsigned, sv[p]) & 0xFFFF0000u) | (unsigned)si[p];
    __syncthreads();

    // ---- leader per row: 4-way merge of sorted-8 -> exact tile top-8 -> gcand ----
    if (t < 64) {
        int pos[4] = {7, 7, 7, 7};
        unsigned res[8];
#pragma unroll
        for (int s = 0; s < 8; ++s) {
            float vb = NEG_INF; int ib = 0x7fffffff; int qb = 0;
#pragma unroll
            for (int q = 0; q < 4; ++q) {
                if (pos[q] >= 0) {
                    unsigned u = candt[(t * 4 + q) * 8 + pos[q]];
                    float v = pkval(u);
                    int  ii = (int)(u & 0xFFFFu);
                    if (v > vb || (v == vb && ii < ib)) { vb = v; ib = ii; qb = q; }
                }
            }
            res[s] = candt[(t * 4 + qb) * 8 + pos[qb]];
            --pos[qb];
        }
        unsigned int* gp = gcand + (size_t)(n0 + t) * 64 + colTile * 8;
        *(uint4*)gp       = make_uint4(res[0], res[1], res[2], res[3]);
        *(uint4*)(gp + 4) = make_uint4(res[4], res[5], res[6], res[7]);
    }
}

// ---------------- kernel 3: merge -> top-16 -> SERIAL fp32 refine -> combine ----------------
#define QS 260
#define SEL_BASE 33792
#define RFV_BASE 35840
#define WL_BASE  37888
#define IL_BASE  38912
#define K3_ARENA 39936
#define NCAND 16

__global__ __launch_bounds__(256, 4) void mergek(const float* __restrict__ x,
                                                 const float* __restrict__ mempool,
                                                 const unsigned int* __restrict__ gcand,
                                                 float* __restrict__ out) {
    __shared__ __align__(16) char arena[K3_ARENA];
    float* candv  = (float*)arena;                   // [32][33]
    int*   candi  = (int*)(arena + 4224);            // [32][33]
    float* qs     = (float*)arena;                   // [32][260] overlay
    float* ot     = (float*)arena;                   // [256][33] overlay
    int*   selidx = (int*)(arena + SEL_BASE);        // [32][16]
    float* refv   = (float*)(arena + RFV_BASE);      // [32][16]
    float* w_lds  = (float*)(arena + WL_BASE);       // [32][8]
    int*   i_lds  = (int*)(arena + IL_BASE);         // [32][8]

    const int t   = threadIdx.x;
    const int n0  = blockIdx.x * 32;
    const int b   = n0 >> 10;
    const int hw0 = n0 & 1023;
    const float* xb = x + (size_t)b * C_ * HW_ + hw0;

    // ---- scan 64 candidates/row: 4 threads/row x 16 ----
    const int srow = t >> 2, stq = t & 3;
    float sv[8]; int si[8];
#pragma unroll
    for (int p = 0; p < 8; ++p) { sv[p] = NEG_INF; si[p] = 0x7fffffff; }
    if (t < 128) {
        const unsigned int* gc = gcand + (size_t)(n0 + srow) * 64 + stq * 16;
#pragma unroll 4
        for (int j = 0; j < 16; ++j) {
            unsigned u = gc[j];
            float v = pkval(u);
            if (v > sv[0]) insert8(v, (int)(u & 0xFFFFu), sv, si);
        }
#pragma unroll
        for (int p = 0; p < 8; ++p) {
            candv[srow * 33 + stq * 8 + p] = sv[p];
            candi[srow * 33 + stq * 8 + p] = si[p];
        }
    }
    __syncthreads();

    // ---- leader: 4-way merge -> approx top-16 ----
    if (t < 32) {
        const int row = t;
        int pos[4] = {7, 7, 7, 7};
        for (int s = 0; s < NCAND; ++s) {
            float vb = NEG_INF; int ib = 0x7fffffff; int qb = 0;
#pragma unroll
            for (int q = 0; q < 4; ++q) {
                if (pos[q] >= 0) {
                    float v = candv[row * 33 + q * 8 + pos[q]];
                    int  ii = candi[row * 33 + q * 8 + pos[q]];
                    if (v > vb || (v == vb && ii < ib)) { vb = v; ib = ii; qb = q; }
                }
            }
            selidx[row * NCAND + s] = ib;
#pragma unroll
            for (int q = 0; q < 4; ++q) if (q == qb) --pos[q];
        }
    }
    __syncthreads();

    // ---- exact fp32 refine: PER-THREAD SERIAL channel-order sum (order load-bearing) ----
    int cnd[2];
    cnd[0] = selidx[t];
    cnd[1] = selidx[t + 256];
    float racc[2] = {0.f, 0.f};
#pragma unroll
    for (int ch = 0; ch < 2; ++ch) {
        const int c0 = ch * 256;
        __syncthreads();
        {
            const int qr = t & 31, qg = t >> 5;
            const float* xp = xb + qr;
#pragma unroll 2
            for (int j = 0; j < 8; ++j) {
                int c = qg * 32 + j * 4;
                f32x4 v;
                v[0] = xp[(size_t)(c0 + c + 0) * HW_];
                v[1] = xp[(size_t)(c0 + c + 1) * HW_];
                v[2] = xp[(size_t)(c0 + c + 2) * HW_];
                v[3] = xp[(size_t)(c0 + c + 3) * HW_];
                *(f32x4*)&qs[qr * QS + c] = v;
            }
        }
        __syncthreads();
#pragma unroll
        for (int pp = 0; pp < 2; ++pp) {
            const int row = (t + 256 * pp) >> 4;
            const float4* mp = (const float4*)(mempool + (size_t)cnd[pp] * C_ + c0);
            const f32x4* qrow = (const f32x4*)&qs[row * QS];
            float a = racc[pp];
#pragma unroll 8
            for (int u = 0; u < 64; ++u) {
                f32x4 q4 = qrow[u];
                float4 m4 = mp[u];
                a = fmaf(q4[0], m4.x, a);
                a = fmaf(q4[1], m4.y, a);
                a = fmaf(q4[2], m4.z, a);
                a = fmaf(q4[3], m4.w, a);
            }
            racc[pp] = a;
        }
    }
    refv[t] = racc[0];
    refv[t + 256] = racc[1];
    __syncthreads();

    // ---- leader: exact top-8 of 16 + softmax ----
    if (t < 32) {
        const int row = t;
        float rv[16]; int ri[16];
#pragma unroll
        for (int s = 0; s < 16; ++s) { rv[s] = refv[row * 16 + s]; ri[s] = selidx[row * 16 + s]; }
        float wv8[8]; int wi8[8];
#pragma unroll
        for (int sel = 0; sel < 8; ++sel) {
            float vb = NEG_INF; int ib = 0x7fffffff; int sb = 0;
            for (int s = 0; s < 16; ++s) {
                if (rv[s] > vb || (rv[s] == vb && ri[s] < ib)) { vb = rv[s]; ib = ri[s]; sb = s; }
            }
            rv[sb] = NEG_INF;
            wv8[sel] = vb; wi8[sel] = ib;
        }
        const float mx = wv8[0];
        float e[8]; float sum = 0.f;
#pragma unroll
        for (int j = 0; j < 8; ++j) { e[j] = expf(wv8[j] - mx); sum += e[j]; }
        const float inv = 1.f / sum;
#pragma unroll
        for (int j = 0; j < 8; ++j) { w_lds[row * 8 + j] = e[j] * inv; i_lds[row * 8 + j] = wi8[j]; }
    }
    __syncthreads();

    // ---- combine: 16-lane group per row, contiguous mempool reads, LDS transpose ----
    const int lg = t & 15;
    const int g  = t >> 4;
#pragma unroll
    for (int half = 0; half < 2; ++half) {
#pragma unroll
        for (int rp = 0; rp < 2; ++rp) {
            const int row = g + rp * 16;
            float wreg[8]; int ireg[8];
#pragma unroll
            for (int j = 0; j < 8; ++j) { wreg[j] = w_lds[row * 8 + j]; ireg[j] = i_lds[row * 8 + j]; }
            f32x4 o[4];
#pragma unroll
            for (int it = 0; it < 4; ++it) o[it] = (f32x4)0.f;
#pragma unroll
            for (int j = 0; j < 8; ++j) {
                const float4* mp = (const float4*)(mempool + (size_t)ireg[j] * C_ + half * 256) + lg;
#pragma unroll
                for (int it = 0; it < 4; ++it) {
                    float4 m4 = mp[it * 16];
                    o[it][0] = fmaf(wreg[j], m4.x, o[it][0]);
                    o[it][1] = fmaf(wreg[j], m4.y, o[it][1]);
                    o[it][2] = fmaf(wreg[j], m4.z, o[it][2]);
                    o[it][3] = fmaf(wreg[j], m4.w, o[it][3]);
                }
            }
#pragma unroll
            for (int it = 0; it < 4; ++it)
#pragma unroll
                for (int i = 0; i < 4; ++i)
                    ot[(it * 64 + lg * 4 + i) * 33 + row] = o[it][i];
        }
        __syncthreads();
        {
            const int r = t & 31, cb = t >> 5;
            float* op = out + (size_t)b * C_ * HW_ + (size_t)(half * 256) * HW_ + hw0 + r;
#pragma unroll 4
            for (int cc = 0; cc < 32; ++cc) {
                int c = cb * 32 + cc;
                op[(size_t)c * HW_] = ot[c * 33 + r];
            }
        }
        __syncthreads();
    }
}

extern "C" void kernel_launch(void* const* d_in, const int* in_sizes, int n_in,
                              void* d_out, int out_size, void* d_ws, size_t ws_size,
                              hipStream_t stream) {
    const float* x       = (const float*)d_in[0];
    const float* mempool = (const float*)d_in[1];
    unsigned short* xbT   = (unsigned short*)d_ws;                        // 32 MiB @0
    unsigned int*   gcand = (unsigned int*)((char*)d_ws + (32u << 20));   //  8 MiB @32M
    unsigned short* membR = (unsigned short*)((char*)d_ws + (48u << 20)); //  2 MiB @48M
    float* o = (float*)d_out;
    xconvk<<<dim3(32, 32), dim3(256), 0, stream>>>(x, xbT);
    convk<<<dim3(512), dim3(256), 0, stream>>>(mempool, membR);
    gemmk<<<dim3(8, 512), dim3(256), 0, stream>>>(xbT, membR, gcand);
    mergek<<<dim3(1024), dim3(256), 0, stream>>>(x, mempool, gcand, o);
}